// Round 10
// baseline (446.639 us; speedup 1.0000x reference)
//
#include <hip/hip_runtime.h>
#include <hip/hip_bf16.h>

// RNN-T joint: out[b,t,u,v] = sum_h relu(enc[b,t,h]+pred[b,u,h]) * W_out[h,v] + b_out[v]
// E=512, P=640, H=512, V=1024, B=4, T=256, U=64  -> M = 65536
//
// Lessons encoded here:
//  - R3/R8: launch_bounds min-waves too high -> unified VGPR+AGPR cap exceeded
//    -> scratch spill -> GBs of fake HBM traffic. Keep acc+staging under cap.
//  - R2/R9: scalar epilogue (consecutive lanes -> consecutive cols) is clean.
//  - This round: BM=64 (one (b,t) row), BN=256, 4 waves 1x4, acc[4][4],
//    launch_bounds(256,3): cap 170 vs ~130 needed -> no spill, 3 blocks/CU.

typedef __attribute__((ext_vector_type(4))) float f32x4;
typedef __attribute__((ext_vector_type(8))) short bf16x8;

__device__ __forceinline__ short f2bf(float x) {
    return __builtin_bit_cast(short, __float2bfloat16(x));
}

// swizzled byte offset inside a [rows][64 bf16] LDS tile (row stride 128 B)
__device__ __forceinline__ int swz(int r, int kByte) {
    return r * 128 + (kByte ^ ((r & 7) << 4));
}

// ---------------------------------------------------------------------------
// merged transpose + cast: 3 weight matrices in one dispatch (select by z)
// ---------------------------------------------------------------------------
__global__ void prep_kernel(const float* __restrict__ W_enc,
                            const float* __restrict__ W_pred,
                            const float* __restrict__ W_out,
                            short* __restrict__ WencT,
                            short* __restrict__ WpredT,
                            short* __restrict__ WoutT) {
    const float* in; short* out; int R, C;
    switch (blockIdx.z) {
        case 0:  in = W_enc;  out = WencT;  R = 512; C = 512;  break;
        case 1:  in = W_pred; out = WpredT; R = 640; C = 512;  break;
        default: in = W_out;  out = WoutT;  R = 512; C = 1024; break;
    }
    const int c0 = blockIdx.x * 32, r0 = blockIdx.y * 32;
    if (c0 >= C || r0 >= R) return;

    __shared__ float tile[32][33];
    const int tx = threadIdx.x, ty = threadIdx.y; // (32,8)
    #pragma unroll
    for (int i = 0; i < 32; i += 8) {
        int r = r0 + ty + i, c = c0 + tx;
        if (r < R && c < C) tile[ty + i][tx] = in[(size_t)r * C + c];
    }
    __syncthreads();
    #pragma unroll
    for (int i = 0; i < 32; i += 8) {
        int oc = c0 + ty + i;  // output row (= input col)
        int orr = r0 + tx;     // output col (= input row)
        if (oc < C && orr < R) out[(size_t)oc * R + orr] = f2bf(tile[tx][ty + i]);
    }
}

// ---------------------------------------------------------------------------
// merged projection GEMM (z=0: enc, z=1: pred):
//   C[M][512] = A[M][K](f32 -> bf16) * BT[512][K](bf16) + bias
// BM=BN=128, BK=64, 256 threads (4 waves 2x2)
// ---------------------------------------------------------------------------
__global__ __launch_bounds__(256, 2)
void proj_kernel(const float* __restrict__ encIn, const float* __restrict__ predIn,
                 const short* __restrict__ WencT, const short* __restrict__ WpredT,
                 const float* __restrict__ b_enc, const float* __restrict__ b_pred,
                 float* __restrict__ encA, float* __restrict__ predA) {
    const float* A; const short* BT; const float* bias; float* C;
    int M, K;
    if (blockIdx.z == 0) {
        A = encIn;  BT = WencT;  bias = b_enc;  C = encA;  M = 1024; K = 512;
    } else {
        A = predIn; BT = WpredT; bias = b_pred; C = predA; M = 256;  K = 640;
        if ((int)blockIdx.x * 128 >= M) return;
    }
    const int N = 512;

    __shared__ __align__(16) unsigned char lA[128 * 128];
    __shared__ __align__(16) unsigned char lB[128 * 128];

    const int tid = threadIdx.x;
    const int m0 = blockIdx.x * 128;
    const int n0 = blockIdx.y * 128;

    const int rSt = tid >> 3;
    const int kc  = tid & 7;

    const int wave = tid >> 6, lane = tid & 63;
    const int wr = wave >> 1, wc = wave & 1;
    const int rA0 = wr * 64 + (lane & 15);
    const int rB0 = wc * 64 + (lane & 15);
    const int kHi = (lane >> 4) * 16;

    f32x4 acc[4][4];
    #pragma unroll
    for (int i = 0; i < 4; ++i)
        #pragma unroll
        for (int j = 0; j < 4; ++j) acc[i][j] = (f32x4)0.0f;

    for (int k0 = 0; k0 < K; k0 += 64) {
        #pragma unroll
        for (int it = 0; it < 4; ++it) {
            int r = rSt + it * 32;
            const float* ap = A + (size_t)(m0 + r) * K + k0 + kc * 8;
            f32x4 a0 = *(const f32x4*)ap;
            f32x4 a1 = *(const f32x4*)(ap + 4);
            bf16x8 v;
            v[0] = f2bf(a0[0]); v[1] = f2bf(a0[1]); v[2] = f2bf(a0[2]); v[3] = f2bf(a0[3]);
            v[4] = f2bf(a1[0]); v[5] = f2bf(a1[1]); v[6] = f2bf(a1[2]); v[7] = f2bf(a1[3]);
            *(bf16x8*)(lA + swz(r, kc * 16)) = v;
        }
        #pragma unroll
        for (int it = 0; it < 4; ++it) {
            int rn = rSt + it * 32;
            const short* wp = BT + (size_t)(n0 + rn) * K + k0 + kc * 8;
            *(bf16x8*)(lB + swz(rn, kc * 16)) = *(const bf16x8*)wp;
        }
        __syncthreads();
        #pragma unroll
        for (int ks = 0; ks < 2; ++ks) {
            const int kb = ks * 64 + kHi;
            bf16x8 af[4], bf[4];
            #pragma unroll
            for (int i = 0; i < 4; ++i) af[i] = *(const bf16x8*)(lA + swz(rA0 + i * 16, kb));
            #pragma unroll
            for (int j = 0; j < 4; ++j) bf[j] = *(const bf16x8*)(lB + swz(rB0 + j * 16, kb));
            #pragma unroll
            for (int i = 0; i < 4; ++i)
                #pragma unroll
                for (int j = 0; j < 4; ++j)
                    acc[i][j] = __builtin_amdgcn_mfma_f32_16x16x32_bf16(af[i], bf[j], acc[i][j], 0, 0, 0);
        }
        __syncthreads();
    }

    // scalar epilogue: consecutive lanes -> consecutive cols (proven clean)
    #pragma unroll
    for (int i = 0; i < 4; ++i) {
        #pragma unroll
        for (int j = 0; j < 4; ++j) {
            int col = n0 + wc * 64 + j * 16 + (lane & 15);
            float bo = bias[col];
            #pragma unroll
            for (int rg = 0; rg < 4; ++rg) {
                int row = m0 + wr * 64 + i * 16 + (lane >> 4) * 4 + rg;
                C[(size_t)row * N + col] = acc[i][j][rg] + bo;
            }
        }
    }
}

// ---------------------------------------------------------------------------
// fused joint kernel: out[m][v], m=(b*256+t)*64+u, A generated on the fly:
//   A[u][h] = relu(enc[b,t,h] + pred[b,u,h])  (bf16; one (b,t) per block)
// BM=64, BN=256, BK=64, K=512. grid (1024, 4), 256 threads (4 waves 1x4).
// LDS: A 8 KB + B 32 KB = 40 KB. launch_bounds(256,3): cap 170 >= ~130 used.
// ---------------------------------------------------------------------------
__global__ __launch_bounds__(256, 3)
void joint_kernel(const float* __restrict__ encA,   // [1024][512]
                  const float* __restrict__ predA,  // [256][512]
                  const short* __restrict__ WoutT,  // [1024][512] bf16
                  const float* __restrict__ b_out,  // [1024]
                  float* __restrict__ out) {        // [65536][1024]
    __shared__ __align__(16) unsigned char lA[64 * 128];    // [64][64] bf16
    __shared__ __align__(16) unsigned char lB[256 * 128];   // [256][64] bf16

    const int tid = threadIdx.x;
    const int m0 = blockIdx.x * 64;          // one (b,t) pair, u = 0..63
    const int n0 = blockIdx.y * 256;
    const int b  = m0 >> 14;
    const int t0 = (m0 >> 6) & 255;

    const int rSt = tid >> 3;          // 0..31
    const int kc  = tid & 7;           // 8-bf16 chunk within BK=64

    const int wave = tid >> 6, lane = tid & 63;   // 4 waves, 1m x 4n
    const int rA0 = lane & 15;
    const int rB0 = wave * 64 + (lane & 15);
    const int kHi = (lane >> 4) * 16;

    const float* encB  = encA + (size_t)(b * 256 + t0) * 512;  // single row
    const float* predB = predA + (size_t)(b * 64) * 512;

    f32x4 acc[4][4];
    #pragma unroll
    for (int i = 0; i < 4; ++i)
        #pragma unroll
        for (int j = 0; j < 4; ++j) acc[i][j] = (f32x4)0.0f;

    for (int k0 = 0; k0 < 512; k0 += 64) {
        // stage A: 64 rows of relu(enc[t] + pred[u]) -> bf16
        #pragma unroll
        for (int it = 0; it < 2; ++it) {
            int u = rSt + it * 32;
            const float* ep = encB + k0 + kc * 8;                    // broadcast row
            const float* pp = predB + (size_t)u * 512 + k0 + kc * 8;
            f32x4 e0 = *(const f32x4*)ep;
            f32x4 e1 = *(const f32x4*)(ep + 4);
            f32x4 p0 = *(const f32x4*)pp;
            f32x4 p1 = *(const f32x4*)(pp + 4);
            bf16x8 v;
            v[0] = f2bf(fmaxf(e0[0] + p0[0], 0.f));
            v[1] = f2bf(fmaxf(e0[1] + p0[1], 0.f));
            v[2] = f2bf(fmaxf(e0[2] + p0[2], 0.f));
            v[3] = f2bf(fmaxf(e0[3] + p0[3], 0.f));
            v[4] = f2bf(fmaxf(e1[0] + p1[0], 0.f));
            v[5] = f2bf(fmaxf(e1[1] + p1[1], 0.f));
            v[6] = f2bf(fmaxf(e1[2] + p1[2], 0.f));
            v[7] = f2bf(fmaxf(e1[3] + p1[3], 0.f));
            *(bf16x8*)(lA + swz(u, kc * 16)) = v;
        }
        // stage B: W_outT tile (256 rows, bf16, k-contiguous)
        #pragma unroll
        for (int it = 0; it < 8; ++it) {
            int rn = rSt + it * 32;
            const short* wp = WoutT + (size_t)(n0 + rn) * 512 + k0 + kc * 8;
            *(bf16x8*)(lB + swz(rn, kc * 16)) = *(const bf16x8*)wp;
        }
        __syncthreads();
        #pragma unroll
        for (int ks = 0; ks < 2; ++ks) {
            const int kb = ks * 64 + kHi;
            bf16x8 af[4], bf[4];
            #pragma unroll
            for (int i = 0; i < 4; ++i) af[i] = *(const bf16x8*)(lA + swz(rA0 + i * 16, kb));
            #pragma unroll
            for (int j = 0; j < 4; ++j) bf[j] = *(const bf16x8*)(lB + swz(rB0 + j * 16, kb));
            #pragma unroll
            for (int i = 0; i < 4; ++i)
                #pragma unroll
                for (int j = 0; j < 4; ++j)
                    acc[i][j] = __builtin_amdgcn_mfma_f32_16x16x32_bf16(af[i], bf[j], acc[i][j], 0, 0, 0);
        }
        __syncthreads();
    }

    // scalar epilogue: consecutive lanes -> consecutive cols (proven clean)
    #pragma unroll
    for (int i = 0; i < 4; ++i) {
        #pragma unroll
        for (int j = 0; j < 4; ++j) {
            int col = n0 + wave * 64 + j * 16 + (lane & 15);
            float bo = b_out[col];
            #pragma unroll
            for (int rg = 0; rg < 4; ++rg) {
                int row = m0 + i * 16 + (lane >> 4) * 4 + rg;
                out[(size_t)row * 1024 + col] = acc[i][j][rg] + bo;
            }
        }
    }
}

// ---------------------------------------------------------------------------
extern "C" void kernel_launch(void* const* d_in, const int* in_sizes, int n_in,
                              void* d_out, int out_size, void* d_ws, size_t ws_size,
                              hipStream_t stream) {
    const float* enc_in  = (const float*)d_in[0];  // (4,256,512)
    const float* pred_in = (const float*)d_in[1];  // (4,64,640)
    const float* W_enc   = (const float*)d_in[2];  // (512,512)
    const float* b_enc   = (const float*)d_in[3];  // (512,)
    const float* W_pred  = (const float*)d_in[4];  // (640,512)
    const float* b_pred  = (const float*)d_in[5];  // (512,)
    const float* W_out   = (const float*)d_in[6];  // (512,1024)
    const float* b_out   = (const float*)d_in[7];  // (1024,)
    float* out = (float*)d_out;                    // (4,256,64,1024)

    // workspace layout
    char* ws = (char*)d_ws;
    float* encA   = (float*)(ws);                  // 1024*512 f32   = 2 MB
    float* predA  = (float*)(ws + 2097152);        //  256*512 f32   = 0.5 MB
    short* WencT  = (short*)(ws + 2621440);        // [512][512] bf16
    short* WpredT = (short*)(ws + 3145728);        // [512][640] bf16
    short* WoutT  = (short*)(ws + 3801088);        // [1024][512] bf16

    // all three weight transposes in one dispatch
    prep_kernel<<<dim3(32, 20, 3), dim3(32, 8), 0, stream>>>(
        W_enc, W_pred, W_out, WencT, WpredT, WoutT);

    // both projections in one dispatch
    proj_kernel<<<dim3(8, 4, 2), 256, 0, stream>>>(
        enc_in, pred_in, WencT, WpredT, b_enc, b_pred, encA, predA);

    // fused joint + output GEMM: BM=64, BN=256
    joint_kernel<<<dim3(65536 / 64, 1024 / 256), 256, 0, stream>>>(
        encA, predA, WoutT, b_out, out);
}

// Round 11
// 364.501 us; speedup vs baseline: 1.2253x; 1.2253x over previous
//
#include <hip/hip_runtime.h>
#include <hip/hip_bf16.h>

// RNN-T joint: out[b,t,u,v] = sum_h relu(enc[b,t,h]+pred[b,u,h]) * W_out[h,v] + b_out[v]
// E=512, P=640, H=512, V=1024, B=4, T=256, U=64  -> M = 65536
//
// Lessons encoded:
//  - R3/R8: exceeding the unified VGPR+AGPR cap (launch_bounds too aggressive)
//    -> scratch spill -> GBs of fake HBM traffic. Stay under the cap.
//  - R2/R9: scalar epilogue (consecutive lanes -> consecutive cols) is clean.
//  - R10: shrinking BM kills compute-intensity per staged B-byte. BM=128/BN=256.
//  - R11: B-staging via global_load_lds from a PRE-SWIZZLED tiled WoutS
//    (inverse-swizzled global source + linear LDS dest + swizzled ds_read).

typedef __attribute__((ext_vector_type(4))) float f32x4;
typedef __attribute__((ext_vector_type(8))) short bf16x8;

__device__ __forceinline__ short f2bf(float x) {
    return __builtin_bit_cast(short, __float2bfloat16(x));
}

// swizzled byte offset inside a [rows][64 bf16] LDS tile (row stride 128 B)
__device__ __forceinline__ int swz(int r, int kByte) {
    return r * 128 + (kByte ^ ((r & 7) << 4));
}

// async global->LDS, 16 B per lane (lds dest: wave-uniform base + lane*16)
__device__ __forceinline__ void gload_lds16(const void* g, void* l) {
    __builtin_amdgcn_global_load_lds(
        (const __attribute__((address_space(1))) unsigned int*)g,
        (__attribute__((address_space(3))) unsigned int*)l, 16, 0, 0);
}

// ---------------------------------------------------------------------------
// merged prep (select by z):
//   z=0: W_enc  [512][512]  -> WencT  [512][512]  (transpose+cast)
//   z=1: W_pred [640][512]  -> WpredT [512][640]  (transpose+cast)
//   z=2: W_out  [512][1024] -> WoutS tiled+swizzled bf16:
//        WoutS[((y*8+ks)*256+rn)*64+ce] = bf16(W_out[ks*64 + (ce^((rn&7)<<3))][y*256+rn])
// ---------------------------------------------------------------------------
__global__ void prep_kernel(const float* __restrict__ W_enc,
                            const float* __restrict__ W_pred,
                            const float* __restrict__ W_out,
                            short* __restrict__ WencT,
                            short* __restrict__ WpredT,
                            short* __restrict__ WoutS) {
    __shared__ float tile[32][33];
    const int tx = threadIdx.x, ty = threadIdx.y; // (32,8)

    if (blockIdx.z == 2) {
        // W_out -> WoutS (tiled + pre-swizzled for global_load_lds)
        const int ks = blockIdx.x, y = blockIdx.y;
        if (ks >= 8 || y >= 4) return;
        const int tid = ty * 32 + tx;
        short* dst = WoutS + (size_t)(y * 8 + ks) * 16384;  // 256*64 bf16 tile
        #pragma unroll
        for (int rg = 0; rg < 8; ++rg) {
            int rn  = rg * 32 + (tid >> 3);
            int ce8 = (tid & 7) * 8;
            bf16x8 v;
            #pragma unroll
            for (int d = 0; d < 8; ++d) {
                int ce = ce8 + d;
                int h  = ks * 64 + (ce ^ ((rn & 7) << 3));
                v[d] = f2bf(W_out[(size_t)h * 1024 + y * 256 + rn]);
            }
            *(bf16x8*)(dst + (size_t)rn * 64 + ce8) = v;  // coalesced write
        }
        return;
    }

    const float* in; short* out; int R, C;
    if (blockIdx.z == 0) { in = W_enc;  out = WencT;  R = 512; C = 512; }
    else                 { in = W_pred; out = WpredT; R = 640; C = 512; }
    const int c0 = blockIdx.x * 32, r0 = blockIdx.y * 32;
    if (c0 >= C || r0 >= R) return;

    #pragma unroll
    for (int i = 0; i < 32; i += 8) {
        int r = r0 + ty + i, c = c0 + tx;
        if (r < R && c < C) tile[ty + i][tx] = in[(size_t)r * C + c];
    }
    __syncthreads();
    #pragma unroll
    for (int i = 0; i < 32; i += 8) {
        int oc = c0 + ty + i;  // output row (= input col)
        int orr = r0 + tx;     // output col (= input row)
        if (oc < C && orr < R) out[(size_t)oc * R + orr] = f2bf(tile[tx][ty + i]);
    }
}

// ---------------------------------------------------------------------------
// merged projection GEMM (z=0: enc, z=1: pred):
//   C[M][512] = A[M][K](f32 -> bf16) * BT[512][K](bf16) + bias
// BM=BN=128, BK=64, 256 threads (4 waves 2x2)
// ---------------------------------------------------------------------------
__global__ __launch_bounds__(256, 2)
void proj_kernel(const float* __restrict__ encIn, const float* __restrict__ predIn,
                 const short* __restrict__ WencT, const short* __restrict__ WpredT,
                 const float* __restrict__ b_enc, const float* __restrict__ b_pred,
                 float* __restrict__ encA, float* __restrict__ predA) {
    const float* A; const short* BT; const float* bias; float* C;
    int M, K;
    if (blockIdx.z == 0) {
        A = encIn;  BT = WencT;  bias = b_enc;  C = encA;  M = 1024; K = 512;
    } else {
        A = predIn; BT = WpredT; bias = b_pred; C = predA; M = 256;  K = 640;
        if ((int)blockIdx.x * 128 >= M) return;
    }
    const int N = 512;

    __shared__ __align__(16) unsigned char lA[128 * 128];
    __shared__ __align__(16) unsigned char lB[128 * 128];

    const int tid = threadIdx.x;
    const int m0 = blockIdx.x * 128;
    const int n0 = blockIdx.y * 128;

    const int rSt = tid >> 3;
    const int kc  = tid & 7;

    const int wave = tid >> 6, lane = tid & 63;
    const int wr = wave >> 1, wc = wave & 1;
    const int rA0 = wr * 64 + (lane & 15);
    const int rB0 = wc * 64 + (lane & 15);
    const int kHi = (lane >> 4) * 16;

    f32x4 acc[4][4];
    #pragma unroll
    for (int i = 0; i < 4; ++i)
        #pragma unroll
        for (int j = 0; j < 4; ++j) acc[i][j] = (f32x4)0.0f;

    for (int k0 = 0; k0 < K; k0 += 64) {
        #pragma unroll
        for (int it = 0; it < 4; ++it) {
            int r = rSt + it * 32;
            const float* ap = A + (size_t)(m0 + r) * K + k0 + kc * 8;
            f32x4 a0 = *(const f32x4*)ap;
            f32x4 a1 = *(const f32x4*)(ap + 4);
            bf16x8 v;
            v[0] = f2bf(a0[0]); v[1] = f2bf(a0[1]); v[2] = f2bf(a0[2]); v[3] = f2bf(a0[3]);
            v[4] = f2bf(a1[0]); v[5] = f2bf(a1[1]); v[6] = f2bf(a1[2]); v[7] = f2bf(a1[3]);
            *(bf16x8*)(lA + swz(r, kc * 16)) = v;
        }
        #pragma unroll
        for (int it = 0; it < 4; ++it) {
            int rn = rSt + it * 32;
            const short* wp = BT + (size_t)(n0 + rn) * K + k0 + kc * 8;
            *(bf16x8*)(lB + swz(rn, kc * 16)) = *(const bf16x8*)wp;
        }
        __syncthreads();
        #pragma unroll
        for (int ks = 0; ks < 2; ++ks) {
            const int kb = ks * 64 + kHi;
            bf16x8 af[4], bf[4];
            #pragma unroll
            for (int i = 0; i < 4; ++i) af[i] = *(const bf16x8*)(lA + swz(rA0 + i * 16, kb));
            #pragma unroll
            for (int j = 0; j < 4; ++j) bf[j] = *(const bf16x8*)(lB + swz(rB0 + j * 16, kb));
            #pragma unroll
            for (int i = 0; i < 4; ++i)
                #pragma unroll
                for (int j = 0; j < 4; ++j)
                    acc[i][j] = __builtin_amdgcn_mfma_f32_16x16x32_bf16(af[i], bf[j], acc[i][j], 0, 0, 0);
        }
        __syncthreads();
    }

    // scalar epilogue: consecutive lanes -> consecutive cols (proven clean)
    #pragma unroll
    for (int i = 0; i < 4; ++i) {
        #pragma unroll
        for (int j = 0; j < 4; ++j) {
            int col = n0 + wc * 64 + j * 16 + (lane & 15);
            float bo = bias[col];
            #pragma unroll
            for (int rg = 0; rg < 4; ++rg) {
                int row = m0 + wr * 64 + i * 16 + (lane >> 4) * 4 + rg;
                C[(size_t)row * N + col] = acc[i][j][rg] + bo;
            }
        }
    }
}

// ---------------------------------------------------------------------------
// fused joint kernel: out[m][v], m=(b*256+t)*64+u, A generated on the fly:
//   A[m][h] = relu(encA[b,t,h] + predA[b,u,h])  (bf16)
// BM=128, BN=256, BK=64, K=512. grid (512, 4), 256 threads (4 waves 2x2).
// B staged via global_load_lds from pre-swizzled WoutS (zero VGPR round-trip).
// LDS: A 16 KB + B 32 KB = 48 KB. launch_bounds(256,2) — R9-proven regime.
// ---------------------------------------------------------------------------
__global__ __launch_bounds__(256, 2)
void joint_kernel(const float* __restrict__ encA,   // [1024][512]
                  const float* __restrict__ predA,  // [256][512]
                  const short* __restrict__ WoutS,  // tiled+swizzled bf16
                  const float* __restrict__ b_out,  // [1024]
                  float* __restrict__ out) {        // [65536][1024]
    __shared__ __align__(16) unsigned char lA[128 * 128];   // [128][64] bf16
    __shared__ __align__(16) unsigned char lB[256 * 128];   // [256][64] bf16 (pre-swizzled data)

    const int tid = threadIdx.x;
    const int m0 = blockIdx.x * 128;
    const int n0 = blockIdx.y * 256;
    const int b  = m0 >> 14;
    const int t0 = (m0 >> 6) & 255;

    const int rSt = tid >> 3;          // 0..31
    const int kc  = tid & 7;           // 8-bf16 chunk within BK=64

    const int wave = tid >> 6, lane = tid & 63;
    const int wr = wave >> 1, wc = wave & 1;   // wave covers 64 m x 128 n
    const int rA0 = wr * 64 + (lane & 15);
    const int rB0 = wc * 128 + (lane & 15);
    const int kHi = (lane >> 4) * 16;

    const float* encB  = encA + (size_t)(b * 256 + t0) * 512;
    const float* predB = predA + (size_t)(b * 64) * 512;
    const char*  wY    = (const char*)WoutS + (size_t)blockIdx.y * 8 * 32768;

    f32x4 acc[4][8];
    #pragma unroll
    for (int i = 0; i < 4; ++i)
        #pragma unroll
        for (int j = 0; j < 8; ++j) acc[i][j] = (f32x4)0.0f;

    for (int k0 = 0; k0 < 512; k0 += 64) {
        // stage B: 8 async 16B global_load_lds per thread from pre-swizzled tile.
        // chunk c = it*4+wave covers LDS rows 8c..8c+7 (linear dest, swizzled data).
        const char* wtile = wY + (size_t)(k0 >> 6) * 32768;
        #pragma unroll
        for (int it = 0; it < 8; ++it) {
            int chunk = it * 4 + wave;
            gload_lds16(wtile + chunk * 1024 + lane * 16, lB + chunk * 1024);
        }
        // stage A: joint tile = relu(enc + pred) -> bf16  (128 rows)
        #pragma unroll
        for (int it = 0; it < 4; ++it) {
            int r = rSt + it * 32;
            int tt = r >> 6;       // 0 or 1
            int u  = r & 63;
            const float* ep = encB + (size_t)tt * 512 + k0 + kc * 8;
            const float* pp = predB + (size_t)u * 512 + k0 + kc * 8;
            f32x4 e0 = *(const f32x4*)ep;
            f32x4 e1 = *(const f32x4*)(ep + 4);
            f32x4 p0 = *(const f32x4*)pp;
            f32x4 p1 = *(const f32x4*)(pp + 4);
            bf16x8 v;
            v[0] = f2bf(fmaxf(e0[0] + p0[0], 0.f));
            v[1] = f2bf(fmaxf(e0[1] + p0[1], 0.f));
            v[2] = f2bf(fmaxf(e0[2] + p0[2], 0.f));
            v[3] = f2bf(fmaxf(e0[3] + p0[3], 0.f));
            v[4] = f2bf(fmaxf(e1[0] + p1[0], 0.f));
            v[5] = f2bf(fmaxf(e1[1] + p1[1], 0.f));
            v[6] = f2bf(fmaxf(e1[2] + p1[2], 0.f));
            v[7] = f2bf(fmaxf(e1[3] + p1[3], 0.f));
            *(bf16x8*)(lA + swz(r, kc * 16)) = v;
        }
        __syncthreads();   // drains vmcnt (global_load_lds) + lgkmcnt
        #pragma unroll
        for (int ks = 0; ks < 2; ++ks) {
            const int kb = ks * 64 + kHi;
            bf16x8 af[4], bf[8];
            #pragma unroll
            for (int i = 0; i < 4; ++i) af[i] = *(const bf16x8*)(lA + swz(rA0 + i * 16, kb));
            #pragma unroll
            for (int j = 0; j < 8; ++j) bf[j] = *(const bf16x8*)(lB + swz(rB0 + j * 16, kb));
            #pragma unroll
            for (int i = 0; i < 4; ++i)
                #pragma unroll
                for (int j = 0; j < 8; ++j)
                    acc[i][j] = __builtin_amdgcn_mfma_f32_16x16x32_bf16(af[i], bf[j], acc[i][j], 0, 0, 0);
        }
        __syncthreads();
    }

    // scalar epilogue: consecutive lanes -> consecutive cols (proven clean)
    #pragma unroll
    for (int i = 0; i < 4; ++i) {
        #pragma unroll
        for (int j = 0; j < 8; ++j) {
            int col = n0 + wc * 128 + j * 16 + (lane & 15);
            float bo = b_out[col];
            #pragma unroll
            for (int rg = 0; rg < 4; ++rg) {
                int row = m0 + wr * 64 + i * 16 + (lane >> 4) * 4 + rg;
                out[(size_t)row * 1024 + col] = acc[i][j][rg] + bo;
            }
        }
    }
}

// ---------------------------------------------------------------------------
extern "C" void kernel_launch(void* const* d_in, const int* in_sizes, int n_in,
                              void* d_out, int out_size, void* d_ws, size_t ws_size,
                              hipStream_t stream) {
    const float* enc_in  = (const float*)d_in[0];  // (4,256,512)
    const float* pred_in = (const float*)d_in[1];  // (4,64,640)
    const float* W_enc   = (const float*)d_in[2];  // (512,512)
    const float* b_enc   = (const float*)d_in[3];  // (512,)
    const float* W_pred  = (const float*)d_in[4];  // (640,512)
    const float* b_pred  = (const float*)d_in[5];  // (512,)
    const float* W_out   = (const float*)d_in[6];  // (512,1024)
    const float* b_out   = (const float*)d_in[7];  // (1024,)
    float* out = (float*)d_out;                    // (4,256,64,1024)

    // workspace layout
    char* ws = (char*)d_ws;
    float* encA   = (float*)(ws);                  // 1024*512 f32   = 2 MB
    float* predA  = (float*)(ws + 2097152);        //  256*512 f32   = 0.5 MB
    short* WencT  = (short*)(ws + 2621440);        // [512][512] bf16
    short* WpredT = (short*)(ws + 3145728);        // [512][640] bf16
    short* WoutS  = (short*)(ws + 3801088);        // tiled+swizzled, 1 MB

    // all three weight preps in one dispatch
    prep_kernel<<<dim3(32, 20, 3), dim3(32, 8), 0, stream>>>(
        W_enc, W_pred, W_out, WencT, WpredT, WoutS);

    // both projections in one dispatch
    proj_kernel<<<dim3(8, 4, 2), 256, 0, stream>>>(
        enc_in, pred_in, WencT, WpredT, b_enc, b_pred, encA, predA);

    // fused joint + output GEMM: BM=128, BN=256
    joint_kernel<<<dim3(65536 / 128, 1024 / 256), 256, 0, stream>>>(
        encA, predA, WoutS, b_out, out);
}